// Round 1
// baseline (236.583 us; speedup 1.0000x reference)
//
#include <hip/hip_runtime.h>
#include <stdint.h>

typedef __bf16 bf16;
typedef __bf16 bf16x8 __attribute__((ext_vector_type(8)));
typedef float  f32x4  __attribute__((ext_vector_type(4)));

#if __has_builtin(__builtin_amdgcn_exp2f)
#define EXP2F(x) __builtin_amdgcn_exp2f(x)
#else
#define EXP2F(x) exp2f(x)
#endif

constexpr int Bn = 8192, Sn = 256, Rn = 8192;
constexpr int BM = 64, BK = 32, KP = 4;
constexpr int KLEN = Rn / KP;  // 2048
constexpr int NC = KLEN / BK;  // 64 chunks per block

// ---------- prep: params (log2-folded) + perb (log2 rates) + inc->bf16 plain convert ----------
__global__ __launch_bounds__(256) void prep_all(
    const float* __restrict__ inc, bf16* __restrict__ incb,
    const float* __restrict__ alpha, const float* __restrict__ beta,
    const float* __restrict__ gam, const int* __restrict__ rm, const int* __restrict__ rtype,
    float4* __restrict__ params, const float* __restrict__ temp,
    const float* __restrict__ cr, const float* __restrict__ fuv, float4* __restrict__ perb) {
  const int g = blockIdx.x, tid = threadIdx.x;
  // incidence fp32 -> bf16, plain elementwise (B-frags now read directly from global)
  size_t e = ((size_t)g * 256 + tid) * 8;
  float4 v0 = *(const float4*)(inc + e);
  float4 v1 = *(const float4*)(inc + e + 4);
  bf16x8 o;
  o[0] = (bf16)v0.x; o[1] = (bf16)v0.y; o[2] = (bf16)v0.z; o[3] = (bf16)v0.w;
  o[4] = (bf16)v1.x; o[5] = (bf16)v1.y; o[6] = (bf16)v1.z; o[7] = (bf16)v1.w;
  *(bf16x8*)(incb + e) = o;
  if (g < 32) {
    int r = g * 256 + tid;
    float a = alpha[r], be = beta[r], gm = gam[r];
    int ty = rtype[r];
    int i0 = rm[2 * r], i1 = rm[2 * r + 1];
    float P = 0.0f, Q = 0.0f;
    float l2A = __log2f(a);
    if (ty == 0) { P = be; Q = gm; }
    else if (ty == 2) { l2A = fmaf(-gm, 1.4426950408889634f, l2A); }  // log2(a*exp(-gm))
    uint32_t bits = (uint32_t)i0 | ((uint32_t)i1 << 10) | ((uint32_t)ty << 20);
    params[r] = make_float4(l2A, P, Q, __uint_as_float(bits));
  } else if (g < 64) {
    int b = (g - 32) * 256 + tid;
    float T = temp[b];
    perb[b] = make_float4(__log2f(T * (1.0f / 300.0f)), 1.4426950408889634f / T,
                          __log2f(cr[b]), __log2f(fuv[b]));
  }
}

// ---------- fused flux + GEMM: B-frags direct from L2, flux via LDS double-buffer ----------
__global__ __launch_bounds__(256, 2) void flux_gemm(
    const float* __restrict__ abund, const float4* __restrict__ perb,
    const float4* __restrict__ params, const bf16* __restrict__ incb,
    float* __restrict__ partial) {
  __shared__ bf16 ab_lds[257 * 64];      // 32,896 B: [s][b]
  __shared__ bf16 flux_lds[2][64 * BK];  // 8,192 B:  [m][k], blocks XOR-swizzled

  const int tid  = threadIdx.x;
  const int lane = tid & 63;
  const int w    = tid >> 6;
  // XCD-aware: consecutive blockIdx round-robins XCDs; same-XCD blocks share kp
  const int x   = blockIdx.x & 7;
  const int jb  = blockIdx.x >> 3;  // 0..63
  const int kp  = x & 3;
  const int m0g = (jb * 2 + (x >> 2)) * BM;
  const int kstart = kp * KLEN;
  const int r16 = lane & 15, q = lane >> 4;
  const int sw16 = (r16 >> 1) & 3;         // frag-read swizzle
  const int fsw  = w ^ ((lane >> 1) & 3);  // flux-write swizzle

  // stage abundances tile transposed [s][b] (once per block)
  {
    int bsub = tid >> 2;
    int scol = (tid & 3) * 64;
    const float* rowp = abund + (size_t)(m0g + bsub) * Sn + scol;
#pragma unroll
    for (int j = 0; j < 16; ++j) {
      float4 v = *(const float4*)(rowp + j * 4);
      int s = scol + j * 4;
      ab_lds[(s + 0) * 64 + bsub] = (bf16)v.x;
      ab_lds[(s + 1) * 64 + bsub] = (bf16)v.y;
      ab_lds[(s + 2) * 64 + bsub] = (bf16)v.z;
      ab_lds[(s + 3) * 64 + bsub] = (bf16)v.w;
    }
    if (tid < 64) ab_lds[256 * 64 + tid] = (bf16)1.0f;  // ones row (species index S)
  }

  float4 pb = perb[m0g + lane];
  const float l2t = pb.x, nitv = -pb.y, l2cr = pb.z, l2fuv = pb.w;

  // flux tile: flux[b=lane][r = kb + w*8 + j], fully in log2 domain
  auto flux_tile = [&](int kb, int buf) {
    const float4* pw = params + kb + w * 8;
    bf16x8 fv;
#pragma unroll
    for (int j = 0; j < 8; ++j) {
      float4 pr = pw[j];
      uint32_t bits = __builtin_amdgcn_readfirstlane(__float_as_uint(pr.w));
      int i0 = (int)(bits & 1023), i1 = (int)((bits >> 10) & 1023), ms = (int)(bits >> 20);
      float a0 = (float)ab_lds[i0 * 64 + lane];
      float a1 = (float)ab_lds[i1 * 64 + lane];
      float lm = (ms == 1) ? l2cr : ((ms == 2) ? l2fuv : 0.0f);
      float arg = fmaf(pr.y, l2t, fmaf(pr.z, nitv, pr.x + lm));
      fv[j] = (bf16)(EXP2F(arg) * (a0 * a1));
    }
    *(bf16x8*)(flux_lds[buf] + lane * BK + fsw * 8) = fv;
  };

  __syncthreads();  // ab ready

  flux_tile(kstart, 0);  // flux chunk 0 -> flux_lds[0]

  f32x4 acc[4][4];
#pragma unroll
  for (int i = 0; i < 4; ++i)
#pragma unroll
    for (int j = 0; j < 4; ++j) acc[i][j] = (f32x4)0.0f;

  // per-lane B-frag base: row = w*64 + nt*16 + r16, col = kstart + q*8 (+ c*BK)
  const bf16* bptr = incb + (size_t)(w * 64 + r16) * Rn + kstart + q * 8;

  for (int c = 0; c < NC; ++c) {
    const int cur = c & 1;
    __syncthreads();  // flux_lds[cur] ready

    bf16x8 af[4], bfr[4];
#pragma unroll
    for (int mt = 0; mt < 4; ++mt)
      af[mt] = *(const bf16x8*)(flux_lds[cur] + (mt * 16 + r16) * BK + (q ^ sw16) * 8);
    // B-frags straight from global (L2-resident 1MB quarter); latency hidden by flux_tile
#pragma unroll
    for (int nt = 0; nt < 4; ++nt)
      bfr[nt] = *(const bf16x8*)(bptr + (size_t)nt * 16 * Rn + c * BK);

    if (c + 1 < NC) flux_tile(kstart + (c + 1) * BK, cur ^ 1);

#pragma unroll
    for (int mt = 0; mt < 4; ++mt)
#pragma unroll
      for (int nt = 0; nt < 4; ++nt)
        acc[mt][nt] = __builtin_amdgcn_mfma_f32_16x16x32_bf16(af[mt], bfr[nt], acc[mt][nt], 0, 0, 0);
  }

  // epilogue: plain stores of the split-K partial
  float* pout = partial + (size_t)kp * Bn * Sn;
#pragma unroll
  for (int mt = 0; mt < 4; ++mt)
#pragma unroll
    for (int nt = 0; nt < 4; ++nt) {
      int col = w * 64 + nt * 16 + r16;
      int row = m0g + mt * 16 + q * 4;
#pragma unroll
      for (int rg = 0; rg < 4; ++rg)
        pout[(size_t)(row + rg) * Sn + col] = acc[mt][nt][rg];
    }
}

// ---------- split-K reduce ----------
__global__ __launch_bounds__(256) void reduce_k(const float* __restrict__ partial,
                                               float* __restrict__ out) {
  size_t i = ((size_t)blockIdx.x * 256 + threadIdx.x) * 4;
  constexpr size_t NS = (size_t)Bn * Sn;
  float4 a = *(const float4*)(partial + i);
  float4 b = *(const float4*)(partial + NS + i);
  float4 c = *(const float4*)(partial + 2 * NS + i);
  float4 d = *(const float4*)(partial + 3 * NS + i);
  float4 r;
  r.x = (a.x + b.x) + (c.x + d.x);
  r.y = (a.y + b.y) + (c.y + d.y);
  r.z = (a.z + b.z) + (c.z + d.z);
  r.w = (a.w + b.w) + (c.w + d.w);
  *(float4*)(out + i) = r;
}

// ---------- launch ----------
extern "C" void kernel_launch(void* const* d_in, const int* in_sizes, int n_in,
                              void* d_out, int out_size, void* d_ws, size_t ws_size,
                              hipStream_t stream) {
  const float* abund = (const float*)d_in[1];
  const float* temp  = (const float*)d_in[2];
  const float* cr    = (const float*)d_in[3];
  const float* fuv   = (const float*)d_in[4];
  const float* inc   = (const float*)d_in[5];
  const float* alpha = (const float*)d_in[6];
  const float* beta  = (const float*)d_in[7];
  const float* gam   = (const float*)d_in[8];
  const int*   rm    = (const int*)d_in[9];
  const int*   rty   = (const int*)d_in[10];
  float* out = (float*)d_out;

  // ws: params f4[8192] | perb f4[8192] | incb bf16[2M] | partial f32[4*2M]  (~36.5 MB)
  float4* params  = (float4*)d_ws;
  float4* perb    = params + Rn;
  bf16*   incb    = (bf16*)(perb + Bn);
  float*  partial = (float*)(incb + (size_t)Sn * Rn);

  prep_all<<<1024, 256, 0, stream>>>(inc, incb, alpha, beta, gam, rm, rty,
                                     params, temp, cr, fuv, perb);
  flux_gemm<<<(Bn / BM) * KP, 256, 0, stream>>>(abund, perb, params, incb, partial);
  reduce_k<<<(Bn * Sn) / 1024, 256, 0, stream>>>(partial, out);
}

// Round 2
// 167.550 us; speedup vs baseline: 1.4120x; 1.4120x over previous
//
#include <hip/hip_runtime.h>
#include <stdint.h>

typedef __bf16 bf16;
typedef __bf16 bf16x8 __attribute__((ext_vector_type(8)));
typedef float  f32x4  __attribute__((ext_vector_type(4)));

#if __has_builtin(__builtin_amdgcn_exp2f)
#define EXP2F(x) __builtin_amdgcn_exp2f(x)
#else
#define EXP2F(x) exp2f(x)
#endif

#define GLD_LDS16(g, l)                                                                    \
  __builtin_amdgcn_global_load_lds((const __attribute__((address_space(1))) uint32_t*)(g), \
                                   (__attribute__((address_space(3))) uint32_t*)(l), 16, 0, 0)

constexpr int Bn = 8192, Sn = 256, Rn = 8192;
constexpr int BM = 64, BK = 32, KP = 4;
constexpr int KLEN = Rn / KP;  // 2048
constexpr int NC = KLEN / BK;  // 64 chunks per block

// ---------- build type-sorted permutation (deterministic scan, 1 block) ----------
// perm[newpos] = old_r ; inv[old_r] = newpos. Sorting r by rtype makes each
// 8-wide param octet type-pure so flux_gemm can branch per-octet (no if-convert).
__global__ __launch_bounds__(256) void build_perm(const int* __restrict__ rtype,
                                                  int* __restrict__ perm,
                                                  int* __restrict__ inv) {
  __shared__ int c0[256], c1[256], c2[256];
  const int t = threadIdx.x;
  const int base = t * 32;
  int ty[32];
  int l0 = 0, l1 = 0, l2 = 0;
#pragma unroll
  for (int i = 0; i < 32; ++i) {
    int v = rtype[base + i];
    ty[i] = v;
    l0 += (v == 0); l1 += (v == 1); l2 += (v == 2);
  }
  c0[t] = l0; c1[t] = l1; c2[t] = l2;
  __syncthreads();
  // inclusive Hillis-Steele scan over 256 threads
  for (int off = 1; off < 256; off <<= 1) {
    int a = (t >= off) ? c0[t - off] : 0;
    int b = (t >= off) ? c1[t - off] : 0;
    int c = (t >= off) ? c2[t - off] : 0;
    __syncthreads();
    c0[t] += a; c1[t] += b; c2[t] += c;
    __syncthreads();
  }
  const int tot0 = c0[255], tot1 = c1[255];
  int o0 = c0[t] - l0;                  // exclusive offsets per bucket
  int o1 = tot0 + c1[t] - l1;
  int o2 = tot0 + tot1 + c2[t] - l2;
#pragma unroll
  for (int i = 0; i < 32; ++i) {
    int v = ty[i];
    int pos = (v == 0) ? o0++ : ((v == 1) ? o1++ : o2++);
    perm[pos] = base + i;
    inv[base + i] = pos;
  }
}

// ---------- prep: params (type-specialized, permuted) + perb + inc->bf16 (perm+row-swizzle) ----------
__global__ __launch_bounds__(256) void prep_all(
    const float* __restrict__ inc, bf16* __restrict__ incb,
    const float* __restrict__ alpha, const float* __restrict__ beta,
    const float* __restrict__ gam, const int* __restrict__ rm, const int* __restrict__ rtype,
    float4* __restrict__ params, const float* __restrict__ temp,
    const float* __restrict__ cr, const float* __restrict__ fuv, float4* __restrict__ perb,
    const int* __restrict__ perm, const int* __restrict__ inv) {
  const int g = blockIdx.x, tid = threadIdx.x;
  // incidence fp32 -> bf16: column-permuted by perm, 8-elem blocks XOR-swizzled by row
  size_t e = ((size_t)g * 256 + tid) * 8;
  int n = (int)(e >> 13);
  int kpos = (int)(e & 8191);
  int sw = (n >> 1) & 3;
  int src = (kpos & ~31) | (((((kpos >> 3) & 3)) ^ sw) << 3);
  const int* pp = perm + src;  // 8 contiguous perm entries (src is 8-aligned)
  const float* rowp = inc + ((size_t)n << 13);
  bf16x8 o;
#pragma unroll
  for (int i = 0; i < 8; ++i) o[i] = (bf16)rowp[pp[i]];
  *(bf16x8*)(incb + e) = o;
  if (g < 32) {
    int r = g * 256 + tid;
    float a = alpha[r], be = beta[r], gm = gam[r];
    int ty = rtype[r];
    int i0 = rm[2 * r], i1 = rm[2 * r + 1];
    float x, P = 0.0f, Q = 0.0f;
    if (ty == 0) { x = __log2f(a); P = be; Q = gm; }       // exp2(x + P*l2t - Q*itv)
    else if (ty == 1) { x = a; }                            // x * cr
    else { x = a * expf(-gm); }                             // x * fuv
    uint32_t bits = (uint32_t)i0 | ((uint32_t)i1 << 10) | ((uint32_t)ty << 20);
    float4 pv = make_float4(x, P, Q, __uint_as_float(bits));
    params[inv[r]] = pv;                                    // scatter into sorted order
  } else if (g < 64) {
    int b = (g - 32) * 256 + tid;
    float T = temp[b];
    perb[b] = make_float4(__log2f(T * (1.0f / 300.0f)), 1.4426950408889634f / T,
                          cr[b], fuv[b]);
  }
}

// ---------- fused flux + GEMM, double-buffered single-barrier K-loop ----------
__global__ __launch_bounds__(256, 2) void flux_gemm(
    const float* __restrict__ abund, const float4* __restrict__ perb,
    const float4* __restrict__ params, const bf16* __restrict__ incb,
    float* __restrict__ partial) {
  __shared__ bf16 ab_lds[257 * 64];        // 32,896 B: [s][b]
  __shared__ bf16 inc_lds[2][256 * BK];    // 32,768 B: [n][k], rows pre-swizzled
  __shared__ bf16 flux_lds[2][64 * BK];    // 8,192 B:  [m][k], blocks XOR-swizzled

  const int tid  = threadIdx.x;
  const int lane = tid & 63;
  const int w    = tid >> 6;
  const int ws   = __builtin_amdgcn_readfirstlane(w);  // provably-uniform warp id
  // XCD-aware: consecutive blockIdx round-robins XCDs; same-XCD blocks share kp
  const int x   = blockIdx.x & 7;
  const int jb  = blockIdx.x >> 3;         // 0..63
  const int kp  = x & 3;
  const int m0g = (jb * 2 + (x >> 2)) * BM;
  const int kstart = kp * KLEN;
  const int r16 = lane & 15, q = lane >> 4;
  const int sw16 = (r16 >> 1) & 3;         // frag-read swizzle
  const int fsw  = w ^ ((lane >> 1) & 3);  // flux-write swizzle

  // issue GLD for chunk 0 early (latency hidden behind ab staging)
#pragma unroll
  for (int i = 0; i < 4; ++i) {
    int rrow = w * 64 + i * 16 + (lane >> 2);
    const bf16* gp = incb + (size_t)rrow * Rn + kstart + (lane & 3) * 8;
    GLD_LDS16(gp, inc_lds[0] + (w * 64 + i * 16) * BK);
  }

  // stage abundances tile transposed [s][b] (once per block)
  {
    int bsub = tid >> 2;
    int scol = (tid & 3) * 64;
    const float* rowp = abund + (size_t)(m0g + bsub) * Sn + scol;
#pragma unroll
    for (int j = 0; j < 16; ++j) {
      float4 v = *(const float4*)(rowp + j * 4);
      int s = scol + j * 4;
      ab_lds[(s + 0) * 64 + bsub] = (bf16)v.x;
      ab_lds[(s + 1) * 64 + bsub] = (bf16)v.y;
      ab_lds[(s + 2) * 64 + bsub] = (bf16)v.z;
      ab_lds[(s + 3) * 64 + bsub] = (bf16)v.w;
    }
    if (tid < 64) ab_lds[256 * 64 + tid] = (bf16)1.0f;  // ones row (species index S)
  }

  float4 pb = perb[m0g + lane];
  const float l2t = pb.x, nitv = -pb.y, crv = pb.z, fuvv = pb.w;

  // flux tile: flux[b=lane][r = kb + ws*8 + j]; octets are type-pure after sort,
  // so one uniform branch per octet picks a lean body (no if-conversion).
  auto flux_tile = [&](int kb, int buf) {
    const float4* pw = params + kb + ws * 8;
    float4 pr[8];
#pragma unroll
    for (int j = 0; j < 8; ++j) pr[j] = pw[j];
    uint32_t b0 = __builtin_amdgcn_readfirstlane(__float_as_uint(pr[0].w));
    uint32_t b7 = __builtin_amdgcn_readfirstlane(__float_as_uint(pr[7].w));
    uint32_t t0 = b0 >> 20, t7 = b7 >> 20;
    bf16x8 fv;
    if (t0 == 0 && t7 == 0) {
      // pure Arrhenius octet
#pragma unroll
      for (int j = 0; j < 8; ++j) {
        uint32_t bits = __builtin_amdgcn_readfirstlane(__float_as_uint(pr[j].w));
        int i0 = (int)(bits & 1023), i1 = (int)((bits >> 10) & 1023);
        float a0 = (float)ab_lds[i0 * 64 + lane];
        float a1 = (float)ab_lds[i1 * 64 + lane];
        float v = EXP2F(fmaf(pr[j].y, l2t, fmaf(pr[j].z, nitv, pr[j].x)));
        fv[j] = (bf16)(v * (a0 * a1));
      }
    } else if (t0 == t7) {
      // pure cr- or fuv-octet: no exp2, shared multiplier
      float mv = (t0 == 1) ? crv : fuvv;
#pragma unroll
      for (int j = 0; j < 8; ++j) {
        uint32_t bits = __builtin_amdgcn_readfirstlane(__float_as_uint(pr[j].w));
        int i0 = (int)(bits & 1023), i1 = (int)((bits >> 10) & 1023);
        float a0 = (float)ab_lds[i0 * 64 + lane];
        float a1 = (float)ab_lds[i1 * 64 + lane];
        fv[j] = (bf16)((pr[j].x * mv) * (a0 * a1));
      }
    } else {
      // mixed boundary octet (<=2 in all of R): generic branchless
#pragma unroll
      for (int j = 0; j < 8; ++j) {
        uint32_t bits = __builtin_amdgcn_readfirstlane(__float_as_uint(pr[j].w));
        int i0 = (int)(bits & 1023), i1 = (int)((bits >> 10) & 1023), ms = (int)(bits >> 20);
        float a0 = (float)ab_lds[i0 * 64 + lane];
        float a1 = (float)ab_lds[i1 * 64 + lane];
        float ve = EXP2F(fmaf(pr[j].y, l2t, fmaf(pr[j].z, nitv, pr[j].x)));
        float vm = pr[j].x * ((ms == 1) ? crv : fuvv);
        float v = (ms == 0) ? ve : vm;
        fv[j] = (bf16)(v * (a0 * a1));
      }
    }
    *(bf16x8*)(flux_lds[buf] + lane * BK + fsw * 8) = fv;
  };

  __syncthreads();  // ab ready + chunk-0 inc staged

  flux_tile(kstart, 0);  // flux chunk 0 -> flux_lds[0]

  f32x4 acc[4][4];
#pragma unroll
  for (int i = 0; i < 4; ++i)
#pragma unroll
    for (int j = 0; j < 4; ++j) acc[i][j] = (f32x4)0.0f;

  for (int c = 0; c < NC; ++c) {
    const int cur = c & 1, nxt = cur ^ 1;
    __syncthreads();  // flux_lds[cur] + inc_lds[cur] ready

    bf16x8 af[4], bfr[4];
#pragma unroll
    for (int mt = 0; mt < 4; ++mt)
      af[mt] = *(const bf16x8*)(flux_lds[cur] + (mt * 16 + r16) * BK + (q ^ sw16) * 8);
#pragma unroll
    for (int nt = 0; nt < 4; ++nt)
      bfr[nt] = *(const bf16x8*)(inc_lds[cur] + (w * 64 + nt * 16 + r16) * BK + (q ^ sw16) * 8);

    if (c + 1 < NC) {
      const int kb = kstart + (c + 1) * BK;
      // async stage next inc tile
#pragma unroll
      for (int i = 0; i < 4; ++i) {
        int rrow = w * 64 + i * 16 + (lane >> 2);
        const bf16* gp = incb + (size_t)rrow * Rn + kb + (lane & 3) * 8;
        GLD_LDS16(gp, inc_lds[nxt] + (w * 64 + i * 16) * BK);
      }
      // next flux tile (independent of this chunk's MFMAs -> overlaps)
      flux_tile(kb, nxt);
    }

    __builtin_amdgcn_s_setprio(1);
#pragma unroll
    for (int mt = 0; mt < 4; ++mt)
#pragma unroll
      for (int nt = 0; nt < 4; ++nt)
        acc[mt][nt] = __builtin_amdgcn_mfma_f32_16x16x32_bf16(af[mt], bfr[nt], acc[mt][nt], 0, 0, 0);
    __builtin_amdgcn_s_setprio(0);
  }

  // epilogue: plain stores of the split-K partial (no atomics, no zero-init needed)
  float* pout = partial + (size_t)kp * Bn * Sn;
#pragma unroll
  for (int mt = 0; mt < 4; ++mt)
#pragma unroll
    for (int nt = 0; nt < 4; ++nt) {
      int col = w * 64 + nt * 16 + r16;
      int row = m0g + mt * 16 + q * 4;
#pragma unroll
      for (int rg = 0; rg < 4; ++rg)
        pout[(size_t)(row + rg) * Sn + col] = acc[mt][nt][rg];
    }
}

// ---------- split-K reduce ----------
__global__ __launch_bounds__(256) void reduce_k(const float* __restrict__ partial,
                                               float* __restrict__ out) {
  size_t i = ((size_t)blockIdx.x * 256 + threadIdx.x) * 4;
  constexpr size_t NS = (size_t)Bn * Sn;
  float4 a = *(const float4*)(partial + i);
  float4 b = *(const float4*)(partial + NS + i);
  float4 c = *(const float4*)(partial + 2 * NS + i);
  float4 d = *(const float4*)(partial + 3 * NS + i);
  float4 r;
  r.x = (a.x + b.x) + (c.x + d.x);
  r.y = (a.y + b.y) + (c.y + d.y);
  r.z = (a.z + b.z) + (c.z + d.z);
  r.w = (a.w + b.w) + (c.w + d.w);
  *(float4*)(out + i) = r;
}

// ---------- launch ----------
extern "C" void kernel_launch(void* const* d_in, const int* in_sizes, int n_in,
                              void* d_out, int out_size, void* d_ws, size_t ws_size,
                              hipStream_t stream) {
  const float* abund = (const float*)d_in[1];
  const float* temp  = (const float*)d_in[2];
  const float* cr    = (const float*)d_in[3];
  const float* fuv   = (const float*)d_in[4];
  const float* inc   = (const float*)d_in[5];
  const float* alpha = (const float*)d_in[6];
  const float* beta  = (const float*)d_in[7];
  const float* gam   = (const float*)d_in[8];
  const int*   rm    = (const int*)d_in[9];
  const int*   rty   = (const int*)d_in[10];
  float* out = (float*)d_out;

  // ws: params f4[8192] | perb f4[8192] | incb bf16[2M] | partial f32[4*2M]  (~36.5 MB)
  // perm/inv alias the head of `partial` (only live between build_perm and prep_all).
  float4* params  = (float4*)d_ws;
  float4* perb    = params + Rn;
  bf16*   incb    = (bf16*)(perb + Bn);
  float*  partial = (float*)(incb + (size_t)Sn * Rn);
  int*    perm    = (int*)partial;
  int*    inv     = perm + Rn;

  build_perm<<<1, 256, 0, stream>>>(rty, perm, inv);
  prep_all<<<1024, 256, 0, stream>>>(inc, incb, alpha, beta, gam, rm, rty,
                                     params, temp, cr, fuv, perb, perm, inv);
  flux_gemm<<<(Bn / BM) * KP, 256, 0, stream>>>(abund, perb, params, incb, partial);
  reduce_k<<<(Bn * Sn) / 1024, 256, 0, stream>>>(partial, out);
}

// Round 4
// 166.636 us; speedup vs baseline: 1.4198x; 1.0055x over previous
//
#include <hip/hip_runtime.h>
#include <stdint.h>

typedef __bf16 bf16;
typedef __bf16 bf16x8 __attribute__((ext_vector_type(8)));
typedef float  f32x4  __attribute__((ext_vector_type(4)));

#if __has_builtin(__builtin_amdgcn_exp2f)
#define EXP2F(x) __builtin_amdgcn_exp2f(x)
#else
#define EXP2F(x) exp2f(x)
#endif

#define GLD_LDS16(g, l)                                                                    \
  __builtin_amdgcn_global_load_lds((const __attribute__((address_space(1))) uint32_t*)(g), \
                                   (__attribute__((address_space(3))) uint32_t*)(l), 16, 0, 0)

constexpr int Bn = 8192, Sn = 256, Rn = 8192;
constexpr int BM = 64, BK = 32, KP = 4;
constexpr int KLEN = Rn / KP;  // 2048
constexpr int NC = KLEN / BK;  // 64 chunks per block

// ---------- build type-sorted permutation (stable, vectorized loads, 1 block) ----------
// perm[newpos] = old_r. Thread t owns r in {t*32+i} (stable partition: within-bucket
// order = original r order — bit-identical perm to the round-2 passing run).
// Loads vectorized as int4 (8 independent 16B loads/thread vs 32 dependent scalars).
__global__ __launch_bounds__(256) void build_perm(const int* __restrict__ rtype,
                                                  int* __restrict__ perm) {
  __shared__ int c0[256], c1[256], c2[256];
  const int t = threadIdx.x;
  const int base = t * 32;
  int4 vv[8];
  const int4* rp = (const int4*)(rtype + base);
#pragma unroll
  for (int k = 0; k < 8; ++k) vv[k] = rp[k];  // independent vector loads
  int ty[32];
#pragma unroll
  for (int k = 0; k < 8; ++k) {
    ty[k * 4 + 0] = vv[k].x; ty[k * 4 + 1] = vv[k].y;
    ty[k * 4 + 2] = vv[k].z; ty[k * 4 + 3] = vv[k].w;
  }
  int l0 = 0, l1 = 0, l2 = 0;
#pragma unroll
  for (int i = 0; i < 32; ++i) {
    int v = ty[i];
    l0 += (v == 0); l1 += (v == 1); l2 += (v == 2);
  }
  c0[t] = l0; c1[t] = l1; c2[t] = l2;
  __syncthreads();
  // inclusive Hillis-Steele scan over 256 threads
  for (int off = 1; off < 256; off <<= 1) {
    int a = (t >= off) ? c0[t - off] : 0;
    int b = (t >= off) ? c1[t - off] : 0;
    int c = (t >= off) ? c2[t - off] : 0;
    __syncthreads();
    c0[t] += a; c1[t] += b; c2[t] += c;
    __syncthreads();
  }
  const int tot0 = c0[255], tot1 = c1[255];
  int o0 = c0[t] - l0;                  // exclusive offsets per bucket
  int o1 = tot0 + c1[t] - l1;
  int o2 = tot0 + tot1 + c2[t] - l2;
#pragma unroll
  for (int i = 0; i < 32; ++i) {
    int v = ty[i];
    int pos = (v == 0) ? o0++ : ((v == 1) ? o1++ : o2++);
    perm[pos] = base + i;
  }
}

// ---------- prep: params (type-specialized, gathered via perm) + perb + inc->bf16 ----------
__global__ __launch_bounds__(256) void prep_all(
    const float* __restrict__ inc, bf16* __restrict__ incb,
    const float* __restrict__ alpha, const float* __restrict__ beta,
    const float* __restrict__ gam, const int* __restrict__ rm, const int* __restrict__ rtype,
    float4* __restrict__ params, const float* __restrict__ temp,
    const float* __restrict__ cr, const float* __restrict__ fuv, float4* __restrict__ perb,
    const int* __restrict__ perm) {
  const int g = blockIdx.x, tid = threadIdx.x;
  // incidence fp32 -> bf16: column-permuted by perm, 8-elem blocks XOR-swizzled by row
  size_t e = ((size_t)g * 256 + tid) * 8;
  int n = (int)(e >> 13);
  int kpos = (int)(e & 8191);
  int sw = (n >> 1) & 3;
  int src = (kpos & ~31) | (((((kpos >> 3) & 3)) ^ sw) << 3);
  const int* pp = perm + src;  // 8 contiguous perm entries (src is 8-aligned)
  const float* rowp = inc + ((size_t)n << 13);
  bf16x8 o;
#pragma unroll
  for (int i = 0; i < 8; ++i) o[i] = (bf16)rowp[pp[i]];
  *(bf16x8*)(incb + e) = o;
  if (g < 32) {
    int p = g * 256 + tid;
    int r = perm[p];  // gather instead of scatter: no inv needed
    float a = alpha[r], be = beta[r], gm = gam[r];
    int ty = rtype[r];
    int i0 = rm[2 * r], i1 = rm[2 * r + 1];
    float x, P = 0.0f, Q = 0.0f;
    if (ty == 0) { x = __log2f(a); P = be; Q = gm; }       // exp2(x + P*l2t - Q*itv)
    else if (ty == 1) { x = a; }                            // x * cr
    else { x = a * expf(-gm); }                             // x * fuv
    uint32_t bits = (uint32_t)i0 | ((uint32_t)i1 << 10) | ((uint32_t)ty << 20);
    params[p] = make_float4(x, P, Q, __uint_as_float(bits));
  } else if (g < 64) {
    int b = (g - 32) * 256 + tid;
    float T = temp[b];
    perb[b] = make_float4(__log2f(T * (1.0f / 300.0f)), 1.4426950408889634f / T,
                          cr[b], fuv[b]);
  }
}

// ---------- fused flux + GEMM, double-buffered single-barrier K-loop (round-2 verbatim) ----------
__global__ __launch_bounds__(256, 2) void flux_gemm(
    const float* __restrict__ abund, const float4* __restrict__ perb,
    const float4* __restrict__ params, const bf16* __restrict__ incb,
    float* __restrict__ partial) {
  __shared__ bf16 ab_lds[257 * 64];        // 32,896 B: [s][b]
  __shared__ bf16 inc_lds[2][256 * BK];    // 32,768 B: [n][k], rows pre-swizzled
  __shared__ bf16 flux_lds[2][64 * BK];    // 8,192 B:  [m][k], blocks XOR-swizzled

  const int tid  = threadIdx.x;
  const int lane = tid & 63;
  const int w    = tid >> 6;
  const int ws   = __builtin_amdgcn_readfirstlane(w);  // provably-uniform warp id
  // XCD-aware: consecutive blockIdx round-robins XCDs; same-XCD blocks share kp
  const int x   = blockIdx.x & 7;
  const int jb  = blockIdx.x >> 3;         // 0..63
  const int kp  = x & 3;
  const int m0g = (jb * 2 + (x >> 2)) * BM;
  const int kstart = kp * KLEN;
  const int r16 = lane & 15, q = lane >> 4;
  const int sw16 = (r16 >> 1) & 3;         // frag-read swizzle
  const int fsw  = w ^ ((lane >> 1) & 3);  // flux-write swizzle

  // issue GLD for chunk 0 early (latency hidden behind ab staging)
#pragma unroll
  for (int i = 0; i < 4; ++i) {
    int rrow = w * 64 + i * 16 + (lane >> 2);
    const bf16* gp = incb + (size_t)rrow * Rn + kstart + (lane & 3) * 8;
    GLD_LDS16(gp, inc_lds[0] + (w * 64 + i * 16) * BK);
  }

  // stage abundances tile transposed [s][b] (once per block)
  {
    int bsub = tid >> 2;
    int scol = (tid & 3) * 64;
    const float* rowp = abund + (size_t)(m0g + bsub) * Sn + scol;
#pragma unroll
    for (int j = 0; j < 16; ++j) {
      float4 v = *(const float4*)(rowp + j * 4);
      int s = scol + j * 4;
      ab_lds[(s + 0) * 64 + bsub] = (bf16)v.x;
      ab_lds[(s + 1) * 64 + bsub] = (bf16)v.y;
      ab_lds[(s + 2) * 64 + bsub] = (bf16)v.z;
      ab_lds[(s + 3) * 64 + bsub] = (bf16)v.w;
    }
    if (tid < 64) ab_lds[256 * 64 + tid] = (bf16)1.0f;  // ones row (species index S)
  }

  float4 pb = perb[m0g + lane];
  const float l2t = pb.x, nitv = -pb.y, crv = pb.z, fuvv = pb.w;

  // flux tile: flux[b=lane][r = kb + ws*8 + j]; octets are type-pure after sort,
  // so one uniform branch per octet picks a lean body (no if-conversion).
  auto flux_tile = [&](int kb, int buf) {
    const float4* pw = params + kb + ws * 8;
    float4 pr[8];
#pragma unroll
    for (int j = 0; j < 8; ++j) pr[j] = pw[j];
    uint32_t b0 = __builtin_amdgcn_readfirstlane(__float_as_uint(pr[0].w));
    uint32_t b7 = __builtin_amdgcn_readfirstlane(__float_as_uint(pr[7].w));
    uint32_t t0 = b0 >> 20, t7 = b7 >> 20;
    bf16x8 fv;
    if (t0 == 0 && t7 == 0) {
      // pure Arrhenius octet
#pragma unroll
      for (int j = 0; j < 8; ++j) {
        uint32_t bits = __builtin_amdgcn_readfirstlane(__float_as_uint(pr[j].w));
        int i0 = (int)(bits & 1023), i1 = (int)((bits >> 10) & 1023);
        float a0 = (float)ab_lds[i0 * 64 + lane];
        float a1 = (float)ab_lds[i1 * 64 + lane];
        float v = EXP2F(fmaf(pr[j].y, l2t, fmaf(pr[j].z, nitv, pr[j].x)));
        fv[j] = (bf16)(v * (a0 * a1));
      }
    } else if (t0 == t7) {
      // pure cr- or fuv-octet: no exp2, shared multiplier
      float mv = (t0 == 1) ? crv : fuvv;
#pragma unroll
      for (int j = 0; j < 8; ++j) {
        uint32_t bits = __builtin_amdgcn_readfirstlane(__float_as_uint(pr[j].w));
        int i0 = (int)(bits & 1023), i1 = (int)((bits >> 10) & 1023);
        float a0 = (float)ab_lds[i0 * 64 + lane];
        float a1 = (float)ab_lds[i1 * 64 + lane];
        fv[j] = (bf16)((pr[j].x * mv) * (a0 * a1));
      }
    } else {
      // mixed boundary octet (<=2 in all of R): generic branchless
#pragma unroll
      for (int j = 0; j < 8; ++j) {
        uint32_t bits = __builtin_amdgcn_readfirstlane(__float_as_uint(pr[j].w));
        int i0 = (int)(bits & 1023), i1 = (int)((bits >> 10) & 1023), ms = (int)(bits >> 20);
        float a0 = (float)ab_lds[i0 * 64 + lane];
        float a1 = (float)ab_lds[i1 * 64 + lane];
        float ve = EXP2F(fmaf(pr[j].y, l2t, fmaf(pr[j].z, nitv, pr[j].x)));
        float vm = pr[j].x * ((ms == 1) ? crv : fuvv);
        float v = (ms == 0) ? ve : vm;
        fv[j] = (bf16)(v * (a0 * a1));
      }
    }
    *(bf16x8*)(flux_lds[buf] + lane * BK + fsw * 8) = fv;
  };

  __syncthreads();  // ab ready + chunk-0 inc staged

  flux_tile(kstart, 0);  // flux chunk 0 -> flux_lds[0]

  f32x4 acc[4][4];
#pragma unroll
  for (int i = 0; i < 4; ++i)
#pragma unroll
    for (int j = 0; j < 4; ++j) acc[i][j] = (f32x4)0.0f;

  for (int c = 0; c < NC; ++c) {
    const int cur = c & 1, nxt = cur ^ 1;
    __syncthreads();  // flux_lds[cur] + inc_lds[cur] ready

    bf16x8 af[4], bfr[4];
#pragma unroll
    for (int mt = 0; mt < 4; ++mt)
      af[mt] = *(const bf16x8*)(flux_lds[cur] + (mt * 16 + r16) * BK + (q ^ sw16) * 8);
#pragma unroll
    for (int nt = 0; nt < 4; ++nt)
      bfr[nt] = *(const bf16x8*)(inc_lds[cur] + (w * 64 + nt * 16 + r16) * BK + (q ^ sw16) * 8);

    if (c + 1 < NC) {
      const int kb = kstart + (c + 1) * BK;
      // async stage next inc tile
#pragma unroll
      for (int i = 0; i < 4; ++i) {
        int rrow = w * 64 + i * 16 + (lane >> 2);
        const bf16* gp = incb + (size_t)rrow * Rn + kb + (lane & 3) * 8;
        GLD_LDS16(gp, inc_lds[nxt] + (w * 64 + i * 16) * BK);
      }
      // next flux tile (independent of this chunk's MFMAs -> overlaps)
      flux_tile(kb, nxt);
    }

    __builtin_amdgcn_s_setprio(1);
#pragma unroll
    for (int mt = 0; mt < 4; ++mt)
#pragma unroll
      for (int nt = 0; nt < 4; ++nt)
        acc[mt][nt] = __builtin_amdgcn_mfma_f32_16x16x32_bf16(af[mt], bfr[nt], acc[mt][nt], 0, 0, 0);
    __builtin_amdgcn_s_setprio(0);
  }

  // epilogue: plain stores of the split-K partial (no atomics, no zero-init needed)
  float* pout = partial + (size_t)kp * Bn * Sn;
#pragma unroll
  for (int mt = 0; mt < 4; ++mt)
#pragma unroll
    for (int nt = 0; nt < 4; ++nt) {
      int col = w * 64 + nt * 16 + r16;
      int row = m0g + mt * 16 + q * 4;
#pragma unroll
      for (int rg = 0; rg < 4; ++rg)
        pout[(size_t)(row + rg) * Sn + col] = acc[mt][nt][rg];
    }
}

// ---------- split-K reduce ----------
__global__ __launch_bounds__(256) void reduce_k(const float* __restrict__ partial,
                                               float* __restrict__ out) {
  size_t i = ((size_t)blockIdx.x * 256 + threadIdx.x) * 4;
  constexpr size_t NS = (size_t)Bn * Sn;
  float4 a = *(const float4*)(partial + i);
  float4 b = *(const float4*)(partial + NS + i);
  float4 c = *(const float4*)(partial + 2 * NS + i);
  float4 d = *(const float4*)(partial + 3 * NS + i);
  float4 r;
  r.x = (a.x + b.x) + (c.x + d.x);
  r.y = (a.y + b.y) + (c.y + d.y);
  r.z = (a.z + b.z) + (c.z + d.z);
  r.w = (a.w + b.w) + (c.w + d.w);
  *(float4*)(out + i) = r;
}

// ---------- launch ----------
extern "C" void kernel_launch(void* const* d_in, const int* in_sizes, int n_in,
                              void* d_out, int out_size, void* d_ws, size_t ws_size,
                              hipStream_t stream) {
  const float* abund = (const float*)d_in[1];
  const float* temp  = (const float*)d_in[2];
  const float* cr    = (const float*)d_in[3];
  const float* fuv   = (const float*)d_in[4];
  const float* inc   = (const float*)d_in[5];
  const float* alpha = (const float*)d_in[6];
  const float* beta  = (const float*)d_in[7];
  const float* gam   = (const float*)d_in[8];
  const int*   rm    = (const int*)d_in[9];
  const int*   rty   = (const int*)d_in[10];
  float* out = (float*)d_out;

  // ws: params f4[8192] | perb f4[8192] | incb bf16[2M] | partial f32[4*2M]  (~36.5 MB)
  // perm aliases the head of `partial` (only live before flux_gemm writes partial).
  float4* params  = (float4*)d_ws;
  float4* perb    = params + Rn;
  bf16*   incb    = (bf16*)(perb + Bn);
  float*  partial = (float*)(incb + (size_t)Sn * Rn);
  int*    perm    = (int*)partial;

  build_perm<<<1, 256, 0, stream>>>(rty, perm);
  prep_all<<<1024, 256, 0, stream>>>(inc, incb, alpha, beta, gam, rm, rty,
                                     params, temp, cr, fuv, perb, perm);
  flux_gemm<<<(Bn / BM) * KP, 256, 0, stream>>>(abund, perb, params, incb, partial);
  reduce_k<<<(Bn * Sn) / 1024, 256, 0, stream>>>(partial, out);
}

// Round 5
// 159.505 us; speedup vs baseline: 1.4832x; 1.0447x over previous
//
#include <hip/hip_runtime.h>
#include <stdint.h>

typedef __bf16 bf16;
typedef __bf16 bf16x8 __attribute__((ext_vector_type(8)));
typedef float  f32x4  __attribute__((ext_vector_type(4)));

#if __has_builtin(__builtin_amdgcn_exp2f)
#define EXP2F(x) __builtin_amdgcn_exp2f(x)
#else
#define EXP2F(x) exp2f(x)
#endif

constexpr int Bn = 8192, Sn = 256, Rn = 8192;
constexpr int BM = 64, BK = 32, KP = 4;
constexpr int KLEN = Rn / KP;  // 2048
constexpr int NC = KLEN / BK;  // 64 chunks per block

// ---------- build type-sorted permutation (stable, vectorized loads, 1 block) ----------
// perm[newpos] = old_r. Thread t owns r in {t*32+i} (stable partition: within-bucket
// order = original r order).
__global__ __launch_bounds__(256) void build_perm(const int* __restrict__ rtype,
                                                  int* __restrict__ perm) {
  __shared__ int c0[256], c1[256], c2[256];
  const int t = threadIdx.x;
  const int base = t * 32;
  int4 vv[8];
  const int4* rp = (const int4*)(rtype + base);
#pragma unroll
  for (int k = 0; k < 8; ++k) vv[k] = rp[k];  // independent vector loads
  int ty[32];
#pragma unroll
  for (int k = 0; k < 8; ++k) {
    ty[k * 4 + 0] = vv[k].x; ty[k * 4 + 1] = vv[k].y;
    ty[k * 4 + 2] = vv[k].z; ty[k * 4 + 3] = vv[k].w;
  }
  int l0 = 0, l1 = 0, l2 = 0;
#pragma unroll
  for (int i = 0; i < 32; ++i) {
    int v = ty[i];
    l0 += (v == 0); l1 += (v == 1); l2 += (v == 2);
  }
  c0[t] = l0; c1[t] = l1; c2[t] = l2;
  __syncthreads();
  // inclusive Hillis-Steele scan over 256 threads
  for (int off = 1; off < 256; off <<= 1) {
    int a = (t >= off) ? c0[t - off] : 0;
    int b = (t >= off) ? c1[t - off] : 0;
    int c = (t >= off) ? c2[t - off] : 0;
    __syncthreads();
    c0[t] += a; c1[t] += b; c2[t] += c;
    __syncthreads();
  }
  const int tot0 = c0[255], tot1 = c1[255];
  int o0 = c0[t] - l0;                  // exclusive offsets per bucket
  int o1 = tot0 + c1[t] - l1;
  int o2 = tot0 + tot1 + c2[t] - l2;
#pragma unroll
  for (int i = 0; i < 32; ++i) {
    int v = ty[i];
    int pos = (v == 0) ? o0++ : ((v == 1) ? o1++ : o2++);
    perm[pos] = base + i;
  }
}

// ---------- prep: params (type-specialized, gathered via perm) + perb + inc->bf16 TILED ----------
// incbT layout: [kp][c][row][32] bf16 — each (kp,c) B-tile contiguous (8192 elems =
// 16 KB), rows in fragment-read order. Logical k = kp*2048 + c*32 + col; columns
// permuted by perm (sorted-by-type order), matching params.
__global__ __launch_bounds__(256) void prep_all(
    const float* __restrict__ inc, bf16* __restrict__ incb,
    const float* __restrict__ alpha, const float* __restrict__ beta,
    const float* __restrict__ gam, const int* __restrict__ rm, const int* __restrict__ rtype,
    float4* __restrict__ params, const float* __restrict__ temp,
    const float* __restrict__ cr, const float* __restrict__ fuv, float4* __restrict__ perb,
    const int* __restrict__ perm) {
  const int g = blockIdx.x, tid = threadIdx.x;
  size_t e = ((size_t)g * 256 + tid) * 8;   // output index in tiled layout
  int col8 = (int)(e & 31);                 // 8-aligned column within tile row
  int row  = (int)((e >> 5) & 255);
  int c    = (int)((e >> 13) & 63);
  int kp   = (int)(e >> 19);
  const int* pp = perm + (kp * KLEN + c * BK + col8);  // 8 contiguous perm entries
  const float* rowp = inc + ((size_t)row << 13);
  bf16x8 o;
#pragma unroll
  for (int i = 0; i < 8; ++i) o[i] = (bf16)rowp[pp[i]];
  *(bf16x8*)(incb + e) = o;
  if (g < 32) {
    int p = g * 256 + tid;
    int r = perm[p];  // gather: params in sorted order
    float a = alpha[r], be = beta[r], gm = gam[r];
    int ty = rtype[r];
    int i0 = rm[2 * r], i1 = rm[2 * r + 1];
    float x, P = 0.0f, Q = 0.0f;
    if (ty == 0) { x = __log2f(a); P = be; Q = gm; }       // exp2(x + P*l2t - Q*itv)
    else if (ty == 1) { x = a; }                            // x * cr
    else { x = a * expf(-gm); }                             // x * fuv
    uint32_t bits = (uint32_t)i0 | ((uint32_t)i1 << 10) | ((uint32_t)ty << 20);
    params[p] = make_float4(x, P, Q, __uint_as_float(bits));
  } else if (g < 64) {
    int b = (g - 32) * 256 + tid;
    float T = temp[b];
    perb[b] = make_float4(__log2f(T * (1.0f / 300.0f)), 1.4426950408889634f / T,
                          cr[b], fuv[b]);
  }
}

// ---------- fused flux + GEMM: B-frags direct from tiled global (L2), flux in LDS ----------
__global__ __launch_bounds__(256, 2) void flux_gemm(
    const float* __restrict__ abund, const float4* __restrict__ perb,
    const float4* __restrict__ params, const bf16* __restrict__ incb,
    float* __restrict__ partial) {
  __shared__ bf16 ab_lds[257 * 64];        // 32,896 B: [s][b]
  __shared__ bf16 flux_lds[2][64 * BK];    // 8,192 B:  [m][k], octets XOR-swizzled

  const int tid  = threadIdx.x;
  const int lane = tid & 63;
  const int w    = tid >> 6;
  const int ws   = __builtin_amdgcn_readfirstlane(w);  // provably-uniform warp id
  // XCD-aware: consecutive blockIdx round-robins XCDs; same-XCD blocks share kp
  const int x   = blockIdx.x & 7;
  const int jb  = blockIdx.x >> 3;         // 0..63
  const int kp  = x & 3;
  const int m0g = (jb * 2 + (x >> 2)) * BM;
  const int kstart = kp * KLEN;
  const int r16 = lane & 15, q = lane >> 4;
  const int sw16 = (r16 >> 1) & 3;         // flux frag-read swizzle
  const int fsw  = w ^ ((lane >> 1) & 3);  // flux-write swizzle

  // stage abundances tile transposed [s][b] (once per block)
  {
    int bsub = tid >> 2;
    int scol = (tid & 3) * 64;
    const float* rowp = abund + (size_t)(m0g + bsub) * Sn + scol;
#pragma unroll
    for (int j = 0; j < 16; ++j) {
      float4 v = *(const float4*)(rowp + j * 4);
      int s = scol + j * 4;
      ab_lds[(s + 0) * 64 + bsub] = (bf16)v.x;
      ab_lds[(s + 1) * 64 + bsub] = (bf16)v.y;
      ab_lds[(s + 2) * 64 + bsub] = (bf16)v.z;
      ab_lds[(s + 3) * 64 + bsub] = (bf16)v.w;
    }
    if (tid < 64) ab_lds[256 * 64 + tid] = (bf16)1.0f;  // ones row (species index S)
  }

  float4 pb = perb[m0g + lane];
  const float l2t = pb.x, nitv = -pb.y, crv = pb.z, fuvv = pb.w;

  // flux tile: flux[b=lane][r = kb + ws*8 + j]; octets type-pure after sort.
  auto flux_tile = [&](int kb, int buf) {
    const float4* pw = params + kb + ws * 8;
    float4 pr[8];
#pragma unroll
    for (int j = 0; j < 8; ++j) pr[j] = pw[j];
    uint32_t b0 = __builtin_amdgcn_readfirstlane(__float_as_uint(pr[0].w));
    uint32_t b7 = __builtin_amdgcn_readfirstlane(__float_as_uint(pr[7].w));
    uint32_t t0 = b0 >> 20, t7 = b7 >> 20;
    bf16x8 fv;
    if (t0 == 0 && t7 == 0) {
      // pure Arrhenius octet
#pragma unroll
      for (int j = 0; j < 8; ++j) {
        uint32_t bits = __builtin_amdgcn_readfirstlane(__float_as_uint(pr[j].w));
        int i0 = (int)(bits & 1023), i1 = (int)((bits >> 10) & 1023);
        float a0 = (float)ab_lds[i0 * 64 + lane];
        float a1 = (float)ab_lds[i1 * 64 + lane];
        float v = EXP2F(fmaf(pr[j].y, l2t, fmaf(pr[j].z, nitv, pr[j].x)));
        fv[j] = (bf16)(v * (a0 * a1));
      }
    } else if (t0 == t7) {
      // pure cr- or fuv-octet: no exp2, shared multiplier
      float mv = (t0 == 1) ? crv : fuvv;
#pragma unroll
      for (int j = 0; j < 8; ++j) {
        uint32_t bits = __builtin_amdgcn_readfirstlane(__float_as_uint(pr[j].w));
        int i0 = (int)(bits & 1023), i1 = (int)((bits >> 10) & 1023);
        float a0 = (float)ab_lds[i0 * 64 + lane];
        float a1 = (float)ab_lds[i1 * 64 + lane];
        fv[j] = (bf16)((pr[j].x * mv) * (a0 * a1));
      }
    } else {
      // mixed boundary octet (<=2 in all of R): generic branchless
#pragma unroll
      for (int j = 0; j < 8; ++j) {
        uint32_t bits = __builtin_amdgcn_readfirstlane(__float_as_uint(pr[j].w));
        int i0 = (int)(bits & 1023), i1 = (int)((bits >> 10) & 1023), ms = (int)(bits >> 20);
        float a0 = (float)ab_lds[i0 * 64 + lane];
        float a1 = (float)ab_lds[i1 * 64 + lane];
        float ve = EXP2F(fmaf(pr[j].y, l2t, fmaf(pr[j].z, nitv, pr[j].x)));
        float vm = pr[j].x * ((ms == 1) ? crv : fuvv);
        float v = (ms == 0) ? ve : vm;
        fv[j] = (bf16)(v * (a0 * a1));
      }
    }
    *(bf16x8*)(flux_lds[buf] + lane * BK + fsw * 8) = fv;
  };

  __syncthreads();  // ab ready

  flux_tile(kstart, 0);  // flux chunk 0 -> flux_lds[0]

  f32x4 acc[4][4];
#pragma unroll
  for (int i = 0; i < 4; ++i)
#pragma unroll
    for (int j = 0; j < 4; ++j) acc[i][j] = (f32x4)0.0f;

  // per-lane B base in tiled incb: tile (kp,c) at (kp*64+c)*8192; within tile,
  // lane reads row (w*64 + nt*16 + r16), 16B at col q*8 -> 1KB coalesced per frag.
  const bf16* bbase = incb + (size_t)(kp * NC) * 8192 + (w * 64 + r16) * BK + q * 8;

  for (int c = 0; c < NC; ++c) {
    const int cur = c & 1, nxt = cur ^ 1;
    __syncthreads();  // flux_lds[cur] ready

    // B-frags direct from global (L2-resident tile; latency hidden by flux_tile below)
    bf16x8 bfr[4];
    const bf16* bp = bbase + (size_t)c * 8192;
#pragma unroll
    for (int nt = 0; nt < 4; ++nt)
      bfr[nt] = *(const bf16x8*)(bp + nt * (16 * BK));

    bf16x8 af[4];
#pragma unroll
    for (int mt = 0; mt < 4; ++mt)
      af[mt] = *(const bf16x8*)(flux_lds[cur] + (mt * 16 + r16) * BK + (q ^ sw16) * 8);

    if (c + 1 < NC) flux_tile(kstart + (c + 1) * BK, nxt);

    __builtin_amdgcn_s_setprio(1);
#pragma unroll
    for (int mt = 0; mt < 4; ++mt)
#pragma unroll
      for (int nt = 0; nt < 4; ++nt)
        acc[mt][nt] = __builtin_amdgcn_mfma_f32_16x16x32_bf16(af[mt], bfr[nt], acc[mt][nt], 0, 0, 0);
    __builtin_amdgcn_s_setprio(0);
  }

  // epilogue: plain stores of the split-K partial (no atomics, no zero-init needed)
  float* pout = partial + (size_t)kp * Bn * Sn;
#pragma unroll
  for (int mt = 0; mt < 4; ++mt)
#pragma unroll
    for (int nt = 0; nt < 4; ++nt) {
      int col = w * 64 + nt * 16 + r16;
      int row = m0g + mt * 16 + q * 4;
#pragma unroll
      for (int rg = 0; rg < 4; ++rg)
        pout[(size_t)(row + rg) * Sn + col] = acc[mt][nt][rg];
    }
}

// ---------- split-K reduce ----------
__global__ __launch_bounds__(256) void reduce_k(const float* __restrict__ partial,
                                               float* __restrict__ out) {
  size_t i = ((size_t)blockIdx.x * 256 + threadIdx.x) * 4;
  constexpr size_t NS = (size_t)Bn * Sn;
  float4 a = *(const float4*)(partial + i);
  float4 b = *(const float4*)(partial + NS + i);
  float4 c = *(const float4*)(partial + 2 * NS + i);
  float4 d = *(const float4*)(partial + 3 * NS + i);
  float4 r;
  r.x = (a.x + b.x) + (c.x + d.x);
  r.y = (a.y + b.y) + (c.y + d.y);
  r.z = (a.z + b.z) + (c.z + d.z);
  r.w = (a.w + b.w) + (c.w + d.w);
  *(float4*)(out + i) = r;
}

// ---------- launch ----------
extern "C" void kernel_launch(void* const* d_in, const int* in_sizes, int n_in,
                              void* d_out, int out_size, void* d_ws, size_t ws_size,
                              hipStream_t stream) {
  const float* abund = (const float*)d_in[1];
  const float* temp  = (const float*)d_in[2];
  const float* cr    = (const float*)d_in[3];
  const float* fuv   = (const float*)d_in[4];
  const float* inc   = (const float*)d_in[5];
  const float* alpha = (const float*)d_in[6];
  const float* beta  = (const float*)d_in[7];
  const float* gam   = (const float*)d_in[8];
  const int*   rm    = (const int*)d_in[9];
  const int*   rty   = (const int*)d_in[10];
  float* out = (float*)d_out;

  // ws: params f4[8192] | perb f4[8192] | incb bf16[2M] | partial f32[4*2M]  (~36.5 MB)
  // perm aliases the head of `partial` (only live before flux_gemm writes partial).
  float4* params  = (float4*)d_ws;
  float4* perb    = params + Rn;
  bf16*   incb    = (bf16*)(perb + Bn);
  float*  partial = (float*)(incb + (size_t)Sn * Rn);
  int*    perm    = (int*)partial;

  build_perm<<<1, 256, 0, stream>>>(rty, perm);
  prep_all<<<1024, 256, 0, stream>>>(inc, incb, alpha, beta, gam, rm, rty,
                                     params, temp, cr, fuv, perb, perm);
  flux_gemm<<<(Bn / BM) * KP, 256, 0, stream>>>(abund, perb, params, incb, partial);
  reduce_k<<<(Bn * Sn) / 1024, 256, 0, stream>>>(partial, out);
}